// Round 3
// baseline (571.183 us; speedup 1.0000x reference)
//
#include <hip/hip_runtime.h>

// Anchor3DHead fused 1x1-conv heads, R3: bf16 MFMA, memory-bound design.
// GEMM: M=pixels(214272), N=72(pad 80), K=384(channels).
// Prep kernel packs W^T[80][384] bf16 + bias[80] f32 into d_ws.
// Main kernel: 4 independent waves/block, 64 px/wave, NO barriers:
//   lane=pixel staging makes the global->LDS transpose free (each lane
//   gathers its own pixel's channels across 32 coalesced row-loads).

constexpr int Bn   = 4;
constexpr int Cc   = 384;
constexpr int Hh   = 248;
constexpr int Ww   = 216;
constexpr int HW   = Hh * Ww;          // 53568 (mult of 16)
constexpr int NPIX = Bn * HW;          // 214272 = 837 * 256
constexpr int NCLS = 18;
constexpr int NREG = 42;
constexpr int NDIR = 12;
constexpr int NPAD = 80;               // padded N (5 tiles of 16)
constexpr int CP   = 40;               // LDS row pad: 32 ch + 8 (16B-aligned, stride 20 words)

typedef __attribute__((ext_vector_type(8))) short short8;
typedef __attribute__((ext_vector_type(4))) float f32x4;

__device__ __forceinline__ unsigned short f2bf(float f) {
    unsigned u = __float_as_uint(f);
    u += 0x7FFFu + ((u >> 16) & 1u);   // round-to-nearest-even
    return (unsigned short)(u >> 16);
}

// ---- prep: Wt[o][c] bf16 (o<80, pad rows zero) + bias[80] f32 into ws ----
__global__ __launch_bounds__(256) void head_prep(
    const float* __restrict__ wc, const float* __restrict__ bc,
    const float* __restrict__ wr, const float* __restrict__ br,
    const float* __restrict__ wd, const float* __restrict__ bd,
    unsigned short* __restrict__ Wt, float* __restrict__ biasp)
{
    int e = blockIdx.x * 256 + threadIdx.x;        // < 30720
    int o = e / Cc, c = e - o * Cc;
    float v = 0.f;
    if (o < NCLS)            v = wc[c * NCLS + o];
    else if (o < NCLS+NREG)  v = wr[c * NREG + (o - NCLS)];
    else if (o < 72)         v = wd[c * NDIR + (o - NCLS - NREG)];
    Wt[e] = f2bf(v);
    if (e < NPAD) {
        float bv = 0.f;
        if (e < NCLS)           bv = bc[e];
        else if (e < NCLS+NREG) bv = br[e - NCLS];
        else if (e < 72)        bv = bd[e - NCLS - NREG];
        biasp[e] = bv;
    }
}

// ---- main ----
__global__ __launch_bounds__(256) void head_mfma(
    const float* __restrict__ x,
    const unsigned short* __restrict__ Wt,
    const float* __restrict__ biasp,
    float* __restrict__ out)
{
    __shared__ short lds[256 * CP];

    const int w    = threadIdx.x >> 6;
    const int lane = threadIdx.x & 63;
    const int n    = lane & 15;            // N index within tile / A row
    const int q    = lane >> 4;            // K segment selector

    const int wpx0 = blockIdx.x * 256 + w * 64;   // wave's pixel base
    const int mypx = wpx0 + lane;
    const int sb   = mypx / HW;
    const int sp   = mypx - sb * HW;
    const float* __restrict__ xs = x + (size_t)sb * (Cc * HW) + sp;

    short* __restrict__ myrow = &lds[(w * 64 + lane) * CP];

    // bias per lane per N-tile (fp32, added post-MFMA)
    float bias_t[5];
    #pragma unroll
    for (int t = 0; t < 5; ++t) bias_t[t] = biasp[16 * t + n];

    f32x4 acc[4][5] = {};

    #pragma unroll 2
    for (int k0 = 0; k0 < Cc; k0 += 32) {
        // stage: 32 channels of my pixel -> LDS row (transpose is free)
        #pragma unroll
        for (int g = 0; g < 4; ++g) {
            float xv[8];
            #pragma unroll
            for (int i = 0; i < 8; ++i)
                xv[i] = xs[(size_t)(k0 + g * 8 + i) * HW];
            short8 pk;
            #pragma unroll
            for (int i = 0; i < 8; ++i) pk[i] = (short)f2bf(xv[i]);
            *(short8*)(myrow + g * 8) = pk;
        }
        // B fragments: Wt rows, L2-resident, one dwordx4 each
        short8 bf[5];
        #pragma unroll
        for (int t = 0; t < 5; ++t)
            bf[t] = *(const short8*)(Wt + (size_t)(16 * t + n) * Cc + k0 + q * 8);
        // A fragments from LDS + MFMA (intra-wave deps only; no barrier)
        #pragma unroll
        for (int st = 0; st < 4; ++st) {
            short8 af = *(const short8*)(&lds[(w * 64 + st * 16 + n) * CP + q * 8]);
            #pragma unroll
            for (int t = 0; t < 5; ++t)
                acc[st][t] = __builtin_amdgcn_mfma_f32_16x16x32_bf16(
                                 af, bf[t], acc[st][t], 0, 0, 0);
        }
    }

    // epilogue: C-layout row = q*4+r (pixel), col = n (output)
    #pragma unroll
    for (int st = 0; st < 4; ++st) {
        const int px = wpx0 + st * 16;         // 16-aligned; b uniform in subtile
        const int bb = px / HW;
        const int pp = px - bb * HW;
        #pragma unroll
        for (int t = 0; t < 5; ++t) {
            const int o = 16 * t + n;
            float* rowp;
            if (o < NCLS)
                rowp = out + ((size_t)bb * NCLS + o) * HW;
            else if (o < NCLS + NREG)
                rowp = out + (size_t)Bn * NCLS * HW + ((size_t)bb * NREG + (o - NCLS)) * HW;
            else
                rowp = out + (size_t)Bn * (NCLS + NREG) * HW + ((size_t)bb * NDIR + (o - 60)) * HW;
            f32x4 v = acc[st][t];
            v[0] += bias_t[t]; v[1] += bias_t[t]; v[2] += bias_t[t]; v[3] += bias_t[t];
            if (o < 72)
                *(f32x4*)(rowp + pp + q * 4) = v;
        }
    }
}

// ---- fallback (R2) if ws too small ----
template<int NA, int LDA, int NB, int LDB>
__device__ __forceinline__ void cohort_run(
    const float* __restrict__ xb,
    const float* __restrict__ wA, const float* __restrict__ bA, float* __restrict__ oA,
    const float* __restrict__ wB, const float* __restrict__ bB, float* __restrict__ oB)
{
    float acc[NA + NB];
    #pragma unroll
    for (int j = 0; j < NA; ++j) acc[j] = bA[j];
    #pragma unroll
    for (int j = 0; j < NB; ++j) acc[NA + j] = bB[j];
    #pragma unroll 4
    for (int c = 0; c < Cc; ++c) {
        const float xv = xb[(size_t)c * HW];
        #pragma unroll
        for (int j = 0; j < NA; ++j) acc[j] = fmaf(xv, wA[c * LDA + j], acc[j]);
        #pragma unroll
        for (int j = 0; j < NB; ++j) acc[NA + j] = fmaf(xv, wB[c * LDB + j], acc[NA + j]);
    }
    #pragma unroll
    for (int j = 0; j < NA; ++j) oA[(size_t)j * HW] = acc[j];
    #pragma unroll
    for (int j = 0; j < NB; ++j) oB[(size_t)j * HW] = acc[NA + j];
}

__global__ __launch_bounds__(256) void head_fused_msplit(
    const float* __restrict__ x,
    const float* __restrict__ wc, const float* __restrict__ bc,
    const float* __restrict__ wr, const float* __restrict__ br,
    const float* __restrict__ wd, const float* __restrict__ bd,
    float* __restrict__ out)
{
    const int w = threadIdx.x >> 6, lane = threadIdx.x & 63;
    const int pix = blockIdx.x * 64 + lane;
    const int b = pix / HW, p = pix - b * HW;
    const float* __restrict__ xb = x + (size_t)b * Cc * HW + p;
    float* __restrict__ outc = out + (size_t)b * NCLS * HW + p;
    float* __restrict__ outr = out + (size_t)Bn * NCLS * HW + (size_t)b * NREG * HW + p;
    float* __restrict__ outd = out + (size_t)Bn * (NCLS + NREG) * HW + (size_t)b * NDIR * HW + p;
    if (w == 0)      cohort_run<18, NCLS, 0, 1>(xb, wc, bc, outc, wc, bc, outc);
    else if (w == 1) cohort_run<18, NREG, 0, 1>(xb, wr, br, outr, wr, br, outr);
    else if (w == 2) cohort_run<18, NREG, 0, 1>(xb, wr + 18, br + 18, outr + (size_t)18 * HW, wr, br, outr);
    else             cohort_run<6, NREG, 12, NDIR>(xb, wr + 36, br + 36, outr + (size_t)36 * HW, wd, bd, outd);
}

extern "C" void kernel_launch(void* const* d_in, const int* in_sizes, int n_in,
                              void* d_out, int out_size, void* d_ws, size_t ws_size,
                              hipStream_t stream) {
    const float* x  = (const float*)d_in[0];
    const float* wc = (const float*)d_in[1];
    const float* bc = (const float*)d_in[2];
    const float* wr = (const float*)d_in[3];
    const float* br = (const float*)d_in[4];
    const float* wd = (const float*)d_in[5];
    const float* bd = (const float*)d_in[6];
    float* out = (float*)d_out;

    const size_t wt_bytes   = (size_t)NPAD * Cc * sizeof(unsigned short); // 61440
    const size_t bias_off   = wt_bytes;
    const size_t need_bytes = bias_off + NPAD * sizeof(float);            // 61760

    if (ws_size >= need_bytes) {
        unsigned short* Wt = (unsigned short*)d_ws;
        float* biasp = (float*)((char*)d_ws + bias_off);
        head_prep<<<dim3((NPAD * Cc) / 256), dim3(256), 0, stream>>>(
            wc, bc, wr, br, wd, bd, Wt, biasp);
        head_mfma<<<dim3(NPIX / 256), dim3(256), 0, stream>>>(x, Wt, biasp, out);
    } else {
        head_fused_msplit<<<dim3(NPIX / 64), dim3(256), 0, stream>>>(
            x, wc, bc, wr, br, wd, bd, out);
    }
}